// Round 3
// baseline (820.476 us; speedup 1.0000x reference)
//
#include <hip/hip_runtime.h>

#define NEG_SLOPE 0.01f

// ---------------------------------------------------------------------------
// Algebraically collapsed pipeline:
//   deg[i]  = 1 + #(edge_orig[1]==i)                       (self-loop included)
//   xd[i]   = x[i] * rsqrt(deg[i])
//   acc[i]  = sum_{e: col_e==i} xd[row_e]
//   s[i]    = rsqrt(deg[i])*acc[i] + x[i]/deg[i]
//   h[i][j] = leakyrelu(s[i]*W[j] + b[j])                  j=0..4
//   uv[i]   = { h·W2[0:5,0]+b2[0], h·W2[0:5,1]+b2[1],      (u = "y" half, gets b2)
//               h·W2[5:10,0],      h·W2[5:10,1] }          (v = "z" half)
//   out[e]  = uv[ei1[e]].xy + uv[ei0[e]].zw
// uv is 200000*16 B = 3.2 MB -> L2-resident per XCD; edge gathers are cheap.
// ---------------------------------------------------------------------------

__global__ void k_init(float* __restrict__ deg, float* __restrict__ acc, int n) {
    int i = blockIdx.x * blockDim.x + threadIdx.x;
    if (i < n) { deg[i] = 1.0f; acc[i] = 0.0f; }  // 1.0 = self-loop
}

__global__ __launch_bounds__(256) void k_count(const int* __restrict__ col,
                                               float* __restrict__ deg, int E) {
    int base = (blockIdx.x * blockDim.x + threadIdx.x) * 4;
    if (base + 3 < E) {
        int4 c = *reinterpret_cast<const int4*>(col + base);
        atomicAdd(&deg[c.x], 1.0f);
        atomicAdd(&deg[c.y], 1.0f);
        atomicAdd(&deg[c.z], 1.0f);
        atomicAdd(&deg[c.w], 1.0f);
    } else {
        for (int e = base; e < E; ++e) atomicAdd(&deg[col[e]], 1.0f);
    }
}

__global__ void k_xd(const float* __restrict__ x, const float* __restrict__ deg,
                     float* __restrict__ xd, int n) {
    int i = blockIdx.x * blockDim.x + threadIdx.x;
    if (i < n) xd[i] = x[i] * rsqrtf(deg[i]);
}

__global__ __launch_bounds__(256) void k_acc(const int* __restrict__ row,
                                             const int* __restrict__ col,
                                             const float* __restrict__ xd,
                                             float* __restrict__ acc, int E) {
    int base = (blockIdx.x * blockDim.x + threadIdx.x) * 4;
    if (base + 3 < E) {
        int4 r = *reinterpret_cast<const int4*>(row + base);
        int4 c = *reinterpret_cast<const int4*>(col + base);
        atomicAdd(&acc[c.x], xd[r.x]);
        atomicAdd(&acc[c.y], xd[r.y]);
        atomicAdd(&acc[c.z], xd[r.z]);
        atomicAdd(&acc[c.w], xd[r.w]);
    } else {
        for (int e = base; e < E; ++e) atomicAdd(&acc[col[e]], xd[row[e]]);
    }
}

__global__ void k_post(const float* __restrict__ x, const float* __restrict__ deg,
                       const float* __restrict__ acc,
                       const float* __restrict__ W, const float* __restrict__ b,
                       const float* __restrict__ W2, const float* __restrict__ b2,
                       float4* __restrict__ uv, int n) {
    int i = blockIdx.x * blockDim.x + threadIdx.x;
    if (i >= n) return;
    float d    = deg[i];
    float dinv = rsqrtf(d);
    float s    = dinv * acc[i] + x[i] / d;
    float u0 = b2[0], u1 = b2[1], v0 = 0.0f, v1 = 0.0f;
#pragma unroll
    for (int j = 0; j < 5; ++j) {
        float h = s * W[j] + b[j];
        h = (h >= 0.0f) ? h : NEG_SLOPE * h;
        u0 += h * W2[j * 2 + 0];
        u1 += h * W2[j * 2 + 1];
        v0 += h * W2[(5 + j) * 2 + 0];
        v1 += h * W2[(5 + j) * 2 + 1];
    }
    uv[i] = make_float4(u0, u1, v0, v1);
}

__global__ __launch_bounds__(256) void k_out(const int* __restrict__ ei0,
                                             const int* __restrict__ ei1,
                                             const float4* __restrict__ uv,
                                             float* __restrict__ out, int E) {
    int base = (blockIdx.x * blockDim.x + threadIdx.x) * 4;
    if (base + 3 < E) {
        int4 a  = *reinterpret_cast<const int4*>(ei0 + base);  // "z" nodes (v part)
        int4 bb = *reinterpret_cast<const int4*>(ei1 + base);  // "y" nodes (u part)
        float4 u0 = uv[bb.x], v0 = uv[a.x];
        float4 u1 = uv[bb.y], v1 = uv[a.y];
        float4 u2 = uv[bb.z], v2 = uv[a.z];
        float4 u3 = uv[bb.w], v3 = uv[a.w];
        float4 o01 = make_float4(u0.x + v0.z, u0.y + v0.w, u1.x + v1.z, u1.y + v1.w);
        float4 o23 = make_float4(u2.x + v2.z, u2.y + v2.w, u3.x + v3.z, u3.y + v3.w);
        *reinterpret_cast<float4*>(out + 2 * base + 0) = o01;
        *reinterpret_cast<float4*>(out + 2 * base + 4) = o23;
    } else {
        for (int e = base; e < E; ++e) {
            float4 u = uv[ei1[e]], v = uv[ei0[e]];
            out[2 * e + 0] = u.x + v.z;
            out[2 * e + 1] = u.y + v.w;
        }
    }
}

extern "C" void kernel_launch(void* const* d_in, const int* in_sizes, int n_in,
                              void* d_out, int out_size, void* d_ws, size_t ws_size,
                              hipStream_t stream) {
    const float* x          = (const float*)d_in[0];
    const int*   edge_index = (const int*)d_in[1];   // [2,E] row-major (int32 per harness)
    const int*   edge_orig  = (const int*)d_in[2];   // [2,E] row-major
    const float* W  = (const float*)d_in[3];
    const float* b  = (const float*)d_in[4];
    const float* W2 = (const float*)d_in[5];         // [10,2] row-major
    const float* b2 = (const float*)d_in[6];

    const int N = in_sizes[0];          // 200000
    const int E = in_sizes[1] / 2;      // 6400000
    float* out = (float*)d_out;

    // workspace layout (floats): uv[4N] | deg[N] | acc[N] | xd[N]  (5.6 MB)
    float*  ws  = (float*)d_ws;
    float4* uv  = (float4*)ws;
    float*  deg = ws + 4 * (size_t)N;
    float*  acc = deg + N;
    float*  xd  = acc + N;

    const int TB = 256;
    const int nb_n = (N + TB - 1) / TB;
    const int nb_e = ((E + 3) / 4 + TB - 1) / TB;

    k_init <<<nb_n, TB, 0, stream>>>(deg, acc, N);
    k_count<<<nb_e, TB, 0, stream>>>(edge_orig + E, deg, E);
    k_xd   <<<nb_n, TB, 0, stream>>>(x, deg, xd, N);
    k_acc  <<<nb_e, TB, 0, stream>>>(edge_orig, edge_orig + E, xd, acc, E);
    k_post <<<nb_n, TB, 0, stream>>>(x, deg, acc, W, b, W2, b2, uv, N);
    k_out  <<<nb_e, TB, 0, stream>>>(edge_index, edge_index + E, uv, out, E);
}

// Round 5
// 813.736 us; speedup vs baseline: 1.0083x; 1.0083x over previous
//
#include <hip/hip_runtime.h>

#define NEG_SLOPE 0.01f
#define NREP 8  // XCDs on MI355X

// ---------------------------------------------------------------------------
// Collapsed pipeline (see r0-r2):
//   deg[i]  = 1 + indegree(edge_orig[1]==i)
//   xd[i]   = x[i]*rsqrt(deg[i]);  acc[i] = sum_{e:col=i} xd[row_e]
//   s[i]    = rsqrt(deg[i])*acc[i] + x[i]/deg[i]
//   h       = leakyrelu(s*W+b);  uv[i] = {h@W2[0:5]+b2, h@W2[5:10]}
//   out[e]  = uv[ei1[e]].xy + uv[ei0[e]].zw
//
// Round-3 change under test: scattered scatter-adds go into per-XCD replicas
// using WORKGROUP-scope relaxed atomics (execute at local TCC, line stays in
// L2) instead of device-scope atomics (r3 PMC: WRITE_SIZE = 6.4M*32B = 200MB,
// 733 GB/s EA-write cap -> 318us each for k_count/k_acc). Replica index is
// the PHYSICAL XCD id from HW_REG_XCC_ID, so every writer of replica r shares
// one L2 -> no cross-XCD coherence needed. Dispatch-boundary release makes
// the replicas visible to the reduce kernels.
// ---------------------------------------------------------------------------

__device__ __forceinline__ int xcd_id() {
    int x;
    asm("s_getreg_b32 %0, hwreg(20, 0, 32)" : "=s"(x));  // HW_REG_XCC_ID (gfx940+), m09
    return x & (NREP - 1);
}

__device__ __forceinline__ void wg_atomic_add(float* p, float v) {
    __hip_atomic_fetch_add(p, v, __ATOMIC_RELAXED, __HIP_MEMORY_SCOPE_WORKGROUP);
}

// zero cntrep+accrep (contiguous 16N floats)
__global__ void k_zero(float4* __restrict__ p, int n4) {
    int i = blockIdx.x * blockDim.x + threadIdx.x;
    int stride = gridDim.x * blockDim.x;
    for (; i < n4; i += stride) p[i] = make_float4(0.f, 0.f, 0.f, 0.f);
}

__global__ __launch_bounds__(256) void k_count_rep(const int* __restrict__ col,
                                                   float* __restrict__ cntrep,
                                                   int E, int N) {
    float* mine = cntrep + (size_t)xcd_id() * N;
    int base = (blockIdx.x * blockDim.x + threadIdx.x) * 4;
    if (base + 3 < E) {
        int4 c = *reinterpret_cast<const int4*>(col + base);
        wg_atomic_add(&mine[c.x], 1.0f);
        wg_atomic_add(&mine[c.y], 1.0f);
        wg_atomic_add(&mine[c.z], 1.0f);
        wg_atomic_add(&mine[c.w], 1.0f);
    } else {
        for (int e = base; e < E; ++e) wg_atomic_add(&mine[col[e]], 1.0f);
    }
}

__global__ void k_degxd(const float* __restrict__ x, const float* __restrict__ cntrep,
                        float* __restrict__ deg, float* __restrict__ xd, int N) {
    int i = blockIdx.x * blockDim.x + threadIdx.x;
    if (i >= N) return;
    float d = 1.0f;  // self-loop
#pragma unroll
    for (int r = 0; r < NREP; ++r) d += cntrep[(size_t)r * N + i];
    deg[i] = d;
    xd[i]  = x[i] * rsqrtf(d);
}

__global__ __launch_bounds__(256) void k_acc_rep(const int* __restrict__ row,
                                                 const int* __restrict__ col,
                                                 const float* __restrict__ xd,
                                                 float* __restrict__ accrep,
                                                 int E, int N) {
    float* mine = accrep + (size_t)xcd_id() * N;
    int base = (blockIdx.x * blockDim.x + threadIdx.x) * 4;
    if (base + 3 < E) {
        int4 r = *reinterpret_cast<const int4*>(row + base);
        int4 c = *reinterpret_cast<const int4*>(col + base);
        wg_atomic_add(&mine[c.x], xd[r.x]);
        wg_atomic_add(&mine[c.y], xd[r.y]);
        wg_atomic_add(&mine[c.z], xd[r.z]);
        wg_atomic_add(&mine[c.w], xd[r.w]);
    } else {
        for (int e = base; e < E; ++e) wg_atomic_add(&mine[col[e]], xd[row[e]]);
    }
}

__global__ void k_post(const float* __restrict__ x, const float* __restrict__ deg,
                       const float* __restrict__ accrep,
                       const float* __restrict__ W, const float* __restrict__ b,
                       const float* __restrict__ W2, const float* __restrict__ b2,
                       float4* __restrict__ uv, int N) {
    int i = blockIdx.x * blockDim.x + threadIdx.x;
    if (i >= N) return;
    float a = 0.0f;
#pragma unroll
    for (int r = 0; r < NREP; ++r) a += accrep[(size_t)r * N + i];
    float d    = deg[i];
    float dinv = rsqrtf(d);
    float s    = dinv * a + x[i] / d;
    float u0 = b2[0], u1 = b2[1], v0 = 0.0f, v1 = 0.0f;
#pragma unroll
    for (int j = 0; j < 5; ++j) {
        float h = s * W[j] + b[j];
        h = (h >= 0.0f) ? h : NEG_SLOPE * h;
        u0 += h * W2[j * 2 + 0];
        u1 += h * W2[j * 2 + 1];
        v0 += h * W2[(5 + j) * 2 + 0];
        v1 += h * W2[(5 + j) * 2 + 1];
    }
    uv[i] = make_float4(u0, u1, v0, v1);
}

__global__ __launch_bounds__(256) void k_out(const int* __restrict__ ei0,
                                             const int* __restrict__ ei1,
                                             const float4* __restrict__ uv,
                                             float* __restrict__ out, int E) {
    int base = (blockIdx.x * blockDim.x + threadIdx.x) * 4;
    if (base + 3 < E) {
        int4 a  = *reinterpret_cast<const int4*>(ei0 + base);  // "z" nodes (v part)
        int4 bb = *reinterpret_cast<const int4*>(ei1 + base);  // "y" nodes (u part)
        float4 u0 = uv[bb.x], v0 = uv[a.x];
        float4 u1 = uv[bb.y], v1 = uv[a.y];
        float4 u2 = uv[bb.z], v2 = uv[a.z];
        float4 u3 = uv[bb.w], v3 = uv[a.w];
        float4 o01 = make_float4(u0.x + v0.z, u0.y + v0.w, u1.x + v1.z, u1.y + v1.w);
        float4 o23 = make_float4(u2.x + v2.z, u2.y + v2.w, u3.x + v3.z, u3.y + v3.w);
        *reinterpret_cast<float4*>(out + 2 * base + 0) = o01;
        *reinterpret_cast<float4*>(out + 2 * base + 4) = o23;
    } else {
        for (int e = base; e < E; ++e) {
            float4 u = uv[ei1[e]], v = uv[ei0[e]];
            out[2 * e + 0] = u.x + v.z;
            out[2 * e + 1] = u.y + v.w;
        }
    }
}

extern "C" void kernel_launch(void* const* d_in, const int* in_sizes, int n_in,
                              void* d_out, int out_size, void* d_ws, size_t ws_size,
                              hipStream_t stream) {
    const float* x          = (const float*)d_in[0];
    const int*   edge_index = (const int*)d_in[1];   // [2,E] row-major, int32
    const int*   edge_orig  = (const int*)d_in[2];   // [2,E] row-major, int32
    const float* W  = (const float*)d_in[3];
    const float* b  = (const float*)d_in[4];
    const float* W2 = (const float*)d_in[5];         // [10,2] row-major
    const float* b2 = (const float*)d_in[6];

    const int N = in_sizes[0];          // 200000
    const int E = in_sizes[1] / 2;      // 6400000
    float* out = (float*)d_out;

    // ws layout (floats): uv[4N] | deg[N] | xd[N] | cntrep[8N] | accrep[8N] = 22N (~17.6 MB)
    float*  ws     = (float*)d_ws;
    float4* uv     = (float4*)ws;
    float*  deg    = ws + 4 * (size_t)N;
    float*  xd     = deg + N;
    float*  cntrep = xd + N;
    float*  accrep = cntrep + (size_t)NREP * N;

    const int TB = 256;
    const int nb_n = (N + TB - 1) / TB;
    const int nb_e = ((E + 3) / 4 + TB - 1) / TB;
    const int nrep4 = (2 * NREP * N) / 4;  // cntrep+accrep as float4 count

    k_zero     <<<2048, TB, 0, stream>>>((float4*)cntrep, nrep4);
    k_count_rep<<<nb_e, TB, 0, stream>>>(edge_orig + E, cntrep, E, N);
    k_degxd    <<<nb_n, TB, 0, stream>>>(x, cntrep, deg, xd, N);
    k_acc_rep  <<<nb_e, TB, 0, stream>>>(edge_orig, edge_orig + E, xd, accrep, E, N);
    k_post     <<<nb_n, TB, 0, stream>>>(x, deg, accrep, W, b, W2, b2, uv, N);
    k_out      <<<nb_e, TB, 0, stream>>>(edge_index, edge_index + E, uv, out, E);
}

// Round 6
// 303.112 us; speedup vs baseline: 2.7068x; 2.6846x over previous
//
#include <hip/hip_runtime.h>

#define NEG_SLOPE 0.01f

// ---- fast-path geometry (N must equal CSZ*NCHK = 200000) -------------------
#define CSZ   12500   // nodes per chunk (LDS hist = 50 KB, under 64 KB static)
#define NCHK  16      // chunks
#define NBB   256     // bucket-builder blocks
#define CAPR  1824    // per-(block,chunk) region capacity: mean 1562.5 + 6.8 sigma
#define NRED  16      // reducer blocks per chunk

// ---------------------------------------------------------------------------
// Collapsed math (r0-r4): s[i] = rsqrt(deg)*acc + x/deg; uv per node; out =
// uv[ei1].xy + uv[ei0].zw.
// r5 change: r3/r5 PMC proved scattered f32 global atomics are memory-side
// write-through (32 B/atomic, 20 G/s) regardless of scope. So: bucket edges
// by col-chunk into per-(block,chunk) private regions (LDS cursors, no global
// atomics), then per-chunk 50 KB LDS histograms accumulate count / xd[row]
// with LDS atomics only; histograms stream out as coalesced writes + 16-way
// reduce fused into k_degxd / k_post. Hot-path global atomic count: ZERO.
// ---------------------------------------------------------------------------

// ============================ fast path ====================================

__global__ __launch_bounds__(256) void k_bucket(const int* __restrict__ row,
                                                const int* __restrict__ col,
                                                unsigned* __restrict__ bkt,
                                                int* __restrict__ cnt, int E) {
    __shared__ unsigned cur[NCHK];
    int tid = threadIdx.x;
    if (tid < NCHK) cur[tid] = 0;
    __syncthreads();
    int units = E >> 2;
    int stride = gridDim.x * blockDim.x;
    for (int u = blockIdx.x * blockDim.x + tid; u < units; u += stride) {
        int4 r4 = reinterpret_cast<const int4*>(row)[u];
        int4 c4 = reinterpret_cast<const int4*>(col)[u];
        int rr[4] = {r4.x, r4.y, r4.z, r4.w};
        int cc[4] = {c4.x, c4.y, c4.z, c4.w};
#pragma unroll
        for (int k = 0; k < 4; ++k) {
            unsigned ci = (unsigned)cc[k] / CSZ;
            unsigned cl = (unsigned)cc[k] - ci * CSZ;
            unsigned p  = (cl << 18) | (unsigned)rr[k];
            unsigned pos = atomicAdd(&cur[ci], 1u);
            if (pos < CAPR)
                bkt[((size_t)blockIdx.x * NCHK + ci) * CAPR + pos] = p;
        }
    }
    // scalar tail (E not multiple of 4)
    if (blockIdx.x == 0 && tid == 0) {
        for (int e = units << 2; e < E; ++e) {
            unsigned ci = (unsigned)col[e] / CSZ;
            unsigned cl = (unsigned)col[e] - ci * CSZ;
            unsigned p  = (cl << 18) | (unsigned)row[e];
            unsigned pos = atomicAdd(&cur[ci], 1u);
            if (pos < CAPR) bkt[((size_t)0 * NCHK + ci) * CAPR + pos] = p;
        }
    }
    __syncthreads();
    if (tid < NCHK) cnt[blockIdx.x * NCHK + tid] = min(cur[tid], (unsigned)CAPR);
}

__global__ __launch_bounds__(256) void k_count_b(const unsigned* __restrict__ bkt,
                                                 const int* __restrict__ cnt,
                                                 unsigned* __restrict__ pcnt) {
    __shared__ unsigned hist[CSZ];
    int tid = threadIdx.x;
    int c  = blockIdx.x >> 4;   // chunk
    int j2 = blockIdx.x & 15;   // reducer lane
    for (int i = tid; i < CSZ; i += 256) hist[i] = 0;
    __syncthreads();
    for (int src = j2; src < NBB; src += NRED) {
        int n = cnt[src * NCHK + c];
        const unsigned* base = bkt + ((size_t)src * NCHK + c) * CAPR;
        int n4 = n >> 2;
        for (int u = tid; u < n4; u += 256) {
            uint4 p4 = reinterpret_cast<const uint4*>(base)[u];
            atomicAdd(&hist[p4.x >> 18], 1u);
            atomicAdd(&hist[p4.y >> 18], 1u);
            atomicAdd(&hist[p4.z >> 18], 1u);
            atomicAdd(&hist[p4.w >> 18], 1u);
        }
        for (int k = (n & ~3) + tid; k < n; k += 256)
            atomicAdd(&hist[base[k] >> 18], 1u);
    }
    __syncthreads();
    unsigned* dst = pcnt + (size_t)blockIdx.x * CSZ;
    for (int i = tid; i < CSZ; i += 256) dst[i] = hist[i];
}

__global__ void k_degxd(const float* __restrict__ x, const unsigned* __restrict__ pcnt,
                        float* __restrict__ deg, float* __restrict__ xd, int N) {
    int i = blockIdx.x * blockDim.x + threadIdx.x;
    if (i >= N) return;
    int c = i / CSZ, il = i - c * CSZ;
    unsigned d = 1;  // self-loop
#pragma unroll
    for (int j = 0; j < NRED; ++j) d += pcnt[((size_t)c * NRED + j) * CSZ + il];
    float df = (float)d;
    deg[i] = df;
    xd[i]  = x[i] * rsqrtf(df);
}

__global__ __launch_bounds__(256) void k_acc_b(const unsigned* __restrict__ bkt,
                                               const int* __restrict__ cnt,
                                               const float* __restrict__ xd,
                                               float* __restrict__ pacc) {
    __shared__ float hist[CSZ];
    int tid = threadIdx.x;
    int c  = blockIdx.x >> 4;
    int j2 = blockIdx.x & 15;
    for (int i = tid; i < CSZ; i += 256) hist[i] = 0.0f;
    __syncthreads();
    for (int src = j2; src < NBB; src += NRED) {
        int n = cnt[src * NCHK + c];
        const unsigned* base = bkt + ((size_t)src * NCHK + c) * CAPR;
        int n4 = n >> 2;
        for (int u = tid; u < n4; u += 256) {
            uint4 p4 = reinterpret_cast<const uint4*>(base)[u];
            atomicAdd(&hist[p4.x >> 18], xd[p4.x & 0x3FFFFu]);
            atomicAdd(&hist[p4.y >> 18], xd[p4.y & 0x3FFFFu]);
            atomicAdd(&hist[p4.z >> 18], xd[p4.z & 0x3FFFFu]);
            atomicAdd(&hist[p4.w >> 18], xd[p4.w & 0x3FFFFu]);
        }
        for (int k = (n & ~3) + tid; k < n; k += 256) {
            unsigned p = base[k];
            atomicAdd(&hist[p >> 18], xd[p & 0x3FFFFu]);
        }
    }
    __syncthreads();
    float* dst = pacc + (size_t)blockIdx.x * CSZ;
    for (int i = tid; i < CSZ; i += 256) dst[i] = hist[i];
}

__global__ void k_post(const float* __restrict__ x, const float* __restrict__ deg,
                       const float* __restrict__ pacc,
                       const float* __restrict__ W, const float* __restrict__ b,
                       const float* __restrict__ W2, const float* __restrict__ b2,
                       float4* __restrict__ uv, int N) {
    int i = blockIdx.x * blockDim.x + threadIdx.x;
    if (i >= N) return;
    int c = i / CSZ, il = i - c * CSZ;
    float a = 0.0f;
#pragma unroll
    for (int j = 0; j < NRED; ++j) a += pacc[((size_t)c * NRED + j) * CSZ + il];
    float d    = deg[i];
    float dinv = rsqrtf(d);
    float s    = dinv * a + x[i] / d;
    float u0 = b2[0], u1 = b2[1], v0 = 0.0f, v1 = 0.0f;
#pragma unroll
    for (int j = 0; j < 5; ++j) {
        float h = s * W[j] + b[j];
        h = (h >= 0.0f) ? h : NEG_SLOPE * h;
        u0 += h * W2[j * 2 + 0];
        u1 += h * W2[j * 2 + 1];
        v0 += h * W2[(5 + j) * 2 + 0];
        v1 += h * W2[(5 + j) * 2 + 1];
    }
    uv[i] = make_float4(u0, u1, v0, v1);
}

__global__ __launch_bounds__(256) void k_out(const int* __restrict__ ei0,
                                             const int* __restrict__ ei1,
                                             const float4* __restrict__ uv,
                                             float* __restrict__ out, int E) {
    int base = (blockIdx.x * blockDim.x + threadIdx.x) * 4;
    if (base + 3 < E) {
        int4 a  = *reinterpret_cast<const int4*>(ei0 + base);
        int4 bb = *reinterpret_cast<const int4*>(ei1 + base);
        float4 u0 = uv[bb.x], v0 = uv[a.x];
        float4 u1 = uv[bb.y], v1 = uv[a.y];
        float4 u2 = uv[bb.z], v2 = uv[a.z];
        float4 u3 = uv[bb.w], v3 = uv[a.w];
        float4 o01 = make_float4(u0.x + v0.z, u0.y + v0.w, u1.x + v1.z, u1.y + v1.w);
        float4 o23 = make_float4(u2.x + v2.z, u2.y + v2.w, u3.x + v3.z, u3.y + v3.w);
        *reinterpret_cast<float4*>(out + 2 * base + 0) = o01;
        *reinterpret_cast<float4*>(out + 2 * base + 4) = o23;
    } else {
        for (int e = base; e < E; ++e) {
            float4 u = uv[ei1[e]], v = uv[ei0[e]];
            out[2 * e + 0] = u.x + v.z;
            out[2 * e + 1] = u.y + v.w;
        }
    }
}

// ===================== fallback path (device atomics) ======================

__global__ void f_init(float* __restrict__ deg, float* __restrict__ acc, int n) {
    int i = blockIdx.x * blockDim.x + threadIdx.x;
    if (i < n) { deg[i] = 1.0f; acc[i] = 0.0f; }
}

__global__ __launch_bounds__(256) void f_count(const int* __restrict__ col,
                                               float* __restrict__ deg, int E) {
    int base = (blockIdx.x * blockDim.x + threadIdx.x) * 4;
    if (base + 3 < E) {
        int4 c = *reinterpret_cast<const int4*>(col + base);
        atomicAdd(&deg[c.x], 1.0f); atomicAdd(&deg[c.y], 1.0f);
        atomicAdd(&deg[c.z], 1.0f); atomicAdd(&deg[c.w], 1.0f);
    } else {
        for (int e = base; e < E; ++e) atomicAdd(&deg[col[e]], 1.0f);
    }
}

__global__ void f_xd(const float* __restrict__ x, const float* __restrict__ deg,
                     float* __restrict__ xd, int n) {
    int i = blockIdx.x * blockDim.x + threadIdx.x;
    if (i < n) xd[i] = x[i] * rsqrtf(deg[i]);
}

__global__ __launch_bounds__(256) void f_acc(const int* __restrict__ row,
                                             const int* __restrict__ col,
                                             const float* __restrict__ xd,
                                             float* __restrict__ acc, int E) {
    int base = (blockIdx.x * blockDim.x + threadIdx.x) * 4;
    if (base + 3 < E) {
        int4 r = *reinterpret_cast<const int4*>(row + base);
        int4 c = *reinterpret_cast<const int4*>(col + base);
        atomicAdd(&acc[c.x], xd[r.x]); atomicAdd(&acc[c.y], xd[r.y]);
        atomicAdd(&acc[c.z], xd[r.z]); atomicAdd(&acc[c.w], xd[r.w]);
    } else {
        for (int e = base; e < E; ++e) atomicAdd(&acc[col[e]], xd[row[e]]);
    }
}

__global__ void f_post(const float* __restrict__ x, const float* __restrict__ deg,
                       const float* __restrict__ acc,
                       const float* __restrict__ W, const float* __restrict__ b,
                       const float* __restrict__ W2, const float* __restrict__ b2,
                       float4* __restrict__ uv, int n) {
    int i = blockIdx.x * blockDim.x + threadIdx.x;
    if (i >= n) return;
    float d    = deg[i];
    float dinv = rsqrtf(d);
    float s    = dinv * acc[i] + x[i] / d;
    float u0 = b2[0], u1 = b2[1], v0 = 0.0f, v1 = 0.0f;
#pragma unroll
    for (int j = 0; j < 5; ++j) {
        float h = s * W[j] + b[j];
        h = (h >= 0.0f) ? h : NEG_SLOPE * h;
        u0 += h * W2[j * 2 + 0];
        u1 += h * W2[j * 2 + 1];
        v0 += h * W2[(5 + j) * 2 + 0];
        v1 += h * W2[(5 + j) * 2 + 1];
    }
    uv[i] = make_float4(u0, u1, v0, v1);
}

// ============================ launch ========================================

extern "C" void kernel_launch(void* const* d_in, const int* in_sizes, int n_in,
                              void* d_out, int out_size, void* d_ws, size_t ws_size,
                              hipStream_t stream) {
    const float* x          = (const float*)d_in[0];
    const int*   edge_index = (const int*)d_in[1];   // [2,E] row-major, int32
    const int*   edge_orig  = (const int*)d_in[2];   // [2,E] row-major, int32
    const float* W  = (const float*)d_in[3];
    const float* b  = (const float*)d_in[4];
    const float* W2 = (const float*)d_in[5];
    const float* b2 = (const float*)d_in[6];

    const int N = in_sizes[0];
    const int E = in_sizes[1] / 2;
    float* out = (float*)d_out;

    const int TB = 256;
    const int nb_n = (N + TB - 1) / TB;
    const int nb_e = ((E + 3) / 4 + TB - 1) / TB;

    // fast-path ws need (4-byte words): uv 4N | deg N | xd N | bkt | cnt | pcnt(=pacc alias)
    const size_t w_uv = 4 * (size_t)N, w_deg = N, w_xd = N;
    const size_t w_bkt = (size_t)NBB * NCHK * CAPR;
    const size_t w_cnt = (size_t)NBB * NCHK;
    const size_t w_p   = (size_t)NCHK * NRED * CSZ;
    const size_t need  = (w_uv + w_deg + w_xd + w_bkt + w_cnt + w_p) * 4;

    float* ws = (float*)d_ws;

    if (N == CSZ * NCHK && ws_size >= need) {
        // ---- fast path: bucket + LDS histograms, zero global atomics ----
        float4*   uv   = (float4*)ws;
        float*    deg  = ws + w_uv;
        float*    xd   = deg + w_deg;
        unsigned* bkt  = (unsigned*)(xd + w_xd);
        int*      cnt  = (int*)(bkt + w_bkt);
        unsigned* pcnt = (unsigned*)(cnt + w_cnt);
        float*    pacc = (float*)pcnt;  // alias: pcnt consumed by k_degxd first

        k_bucket <<<NBB, TB, 0, stream>>>(edge_orig, edge_orig + E, bkt, cnt, E);
        k_count_b<<<NCHK * NRED, TB, 0, stream>>>(bkt, cnt, pcnt);
        k_degxd  <<<nb_n, TB, 0, stream>>>(x, pcnt, deg, xd, N);
        k_acc_b  <<<NCHK * NRED, TB, 0, stream>>>(bkt, cnt, xd, pacc);
        k_post   <<<nb_n, TB, 0, stream>>>(x, deg, pacc, W, b, W2, b2, uv, N);
        k_out    <<<nb_e, TB, 0, stream>>>(edge_index, edge_index + E, uv, out, E);
    } else {
        // ---- fallback: known-correct device-atomic path (r2/r3) ----
        float4* uv  = (float4*)ws;
        float*  deg = ws + 4 * (size_t)N;
        float*  acc = deg + N;
        float*  xd  = acc + N;
        f_init <<<nb_n, TB, 0, stream>>>(deg, acc, N);
        f_count<<<nb_e, TB, 0, stream>>>(edge_orig + E, deg, E);
        f_xd   <<<nb_n, TB, 0, stream>>>(x, deg, xd, N);
        f_acc  <<<nb_e, TB, 0, stream>>>(edge_orig, edge_orig + E, xd, acc, E);
        f_post <<<nb_n, TB, 0, stream>>>(x, deg, acc, W, b, W2, b2, uv, N);
        k_out  <<<nb_e, TB, 0, stream>>>(edge_index, edge_index + E, uv, out, E);
    }
}